// Round 17
// baseline (90.422 us; speedup 1.0000x reference)
//
#include <hip/hip_runtime.h>
#include <math.h>

#define CDIM 1024
#define RDIM 100
#define NBAGS 8192
#define RPAD 112   // 7 r-tiles of 16

typedef float floatx4 __attribute__((ext_vector_type(4)));
typedef short bf16x8 __attribute__((ext_vector_type(8)));

__device__ __forceinline__ float dot4(float4 a, float4 b) {
    return a.x * b.x + a.y * b.y + a.z * b.z + a.w * b.w;
}

// fp32 -> bf16 round-to-nearest-even
__device__ __forceinline__ unsigned short f2bf(float f) {
    unsigned int u = __builtin_bit_cast(unsigned int, f);
    u += 0x7FFFu + ((u >> 16) & 1u);
    return (unsigned short)(u >> 16);
}

// bf16 -> fp32
__device__ __forceinline__ float bf2f(unsigned short u) {
    return __builtin_bit_cast(float, (unsigned int)u << 16);
}

#define LOADROW(D0, D1, D2, D3, ri)                                          \
    {                                                                        \
        const float4* p_ = (const float4*)(X + (size_t)(ri) * CDIM);         \
        D0 = p_[lane];       D1 = p_[lane + 64];                             \
        D2 = p_[lane + 128]; D3 = p_[lane + 192];                            \
    }

// Online-softmax update with one row held in named registers.
#define COMPUTE_ROW(A0, A1, A2, A3)                                          \
    {                                                                        \
        float p = dot4(A0, c0) + dot4(A1, c1) + dot4(A2, c2) + dot4(A3, c3); \
        p += __shfl_xor(p, 1);                                               \
        p += __shfl_xor(p, 2);                                               \
        p += __shfl_xor(p, 4);                                               \
        p += __shfl_xor(p, 8);                                               \
        p += __shfl_xor(p, 16);                                              \
        p += __shfl_xor(p, 32);                                              \
        const float newm = fmaxf(m, p);                                      \
        const float corr = __expf(m - newm);  /* 0 on first row */           \
        const float wgt  = __expf(p - newm);                                 \
        denom = fmaf(denom, corr, wgt);                                      \
        a0.x = fmaf(a0.x, corr, wgt * A0.x); a0.y = fmaf(a0.y, corr, wgt * A0.y); \
        a0.z = fmaf(a0.z, corr, wgt * A0.z); a0.w = fmaf(a0.w, corr, wgt * A0.w); \
        a1.x = fmaf(a1.x, corr, wgt * A1.x); a1.y = fmaf(a1.y, corr, wgt * A1.y); \
        a1.z = fmaf(a1.z, corr, wgt * A1.z); a1.w = fmaf(a1.w, corr, wgt * A1.w); \
        a2.x = fmaf(a2.x, corr, wgt * A2.x); a2.y = fmaf(a2.y, corr, wgt * A2.y); \
        a2.z = fmaf(a2.z, corr, wgt * A2.z); a2.w = fmaf(a2.w, corr, wgt * A2.w); \
        a3.x = fmaf(a3.x, corr, wgt * A3.x); a3.y = fmaf(a3.y, corr, wgt * A3.y); \
        a3.z = fmaf(a3.z, corr, wgt * A3.z); a3.w = fmaf(a3.w, corr, wgt * A3.w); \
        m = newm;                                                            \
    }

// Kernel 1: one BLOCK (4 waves) per bag, rows striped across waves (stride 4),
// 2-deep prefetch — identical load/compute to round 12. Round-17 change: NO
// cross-wave merge, NO LDS, NO __syncthreads. Each wave writes its RAW
// partial state: bf16 accumulator row partial[bag][w][1024] (coalesced 8B/lane
// stores) + (m, denom) to pmd[bag][w]. k2 performs the softmax combine.
// Rationale: the merge phase (~700cy of barriers+LDS with zero loads in
// flight) was ~30% of avg block lifetime -> ~75% load duty cycle -> k1 ran at
// 5.1 of ~6.5 TB/s. Blocks are now pure load->compute->store pipelines.
// Blocks >= NBAGS build PW.
__global__ __launch_bounds__(256) void bag_softmax_partial(
    const float* __restrict__ X,
    const float* __restrict__ Constraints,
    const int* __restrict__ scope,
    const int* __restrict__ rel,
    const float* __restrict__ W,
    unsigned short* __restrict__ partial,
    float* __restrict__ pmd,
    unsigned short* __restrict__ PW)
{
    const int lane = threadIdx.x & 63;
    const int w    = threadIdx.x >> 6;

    if (blockIdx.x >= NBAGS) {
        // Build PW: one r-row per block (112 blocks), 4 channels per thread.
        // PW[((kc*7+t)*64 + lane)*8 + i] = W[t*16+(lane&15)][kc*32+(lane>>4)*8+i]
        const int rr = blockIdx.x - NBAGS;          // 0..111
        const int t  = threadIdx.x;                 // channels c = 4t..4t+3
        const int kc  = t >> 3;
        const int sub = (t >> 1) & 3;
        const int i0  = (t & 1) * 4;
        ushort4 o = {0, 0, 0, 0};
        if (rr < RDIM) {
            float4 v = *(const float4*)(W + (size_t)rr * CDIM + t * 4);
            o.x = f2bf(v.x); o.y = f2bf(v.y); o.z = f2bf(v.z); o.w = f2bf(v.w);
        }
        const int tt = rr >> 4, rl = rr & 15;
        *(ushort4*)(PW + ((size_t)(kc * 7 + tt) * 64 + sub * 16 + rl) * 8 + i0) = o;
        return;
    }

    const int bag = blockIdx.x;
    const int s = scope[2 * bag];
    const int e = scope[2 * bag + 1];
    const int r = rel[bag];

    const float4* conp = (const float4*)(Constraints + (size_t)r * CDIM);
    const float4 c0 = conp[lane];
    const float4 c1 = conp[lane + 64];
    const float4 c2 = conp[lane + 128];
    const float4 c3 = conp[lane + 192];

    float4 a0 = {0.f, 0.f, 0.f, 0.f};
    float4 a1 = {0.f, 0.f, 0.f, 0.f};
    float4 a2 = {0.f, 0.f, 0.f, 0.f};
    float4 a3 = {0.f, 0.f, 0.f, 0.f};
    float m = -INFINITY;
    float denom = 0.f;

    int row = s + w;
    if (row < e) {                    // uniform per wave
        float4 A0, A1, A2, A3;        // row
        float4 B0, B1, B2, B3;        // row+4
        float4 C0, C1, C2, C3;        // row+8 (rotating)

        LOADROW(A0, A1, A2, A3, row)
        if (row + 4 < e) LOADROW(B0, B1, B2, B3, row + 4)

        for (; row + 8 < e; row += 4) {
            LOADROW(C0, C1, C2, C3, row + 8)
            __builtin_amdgcn_sched_barrier(0);
            COMPUTE_ROW(A0, A1, A2, A3)
            A0 = B0; A1 = B1; A2 = B2; A3 = B3;
            B0 = C0; B1 = C1; B2 = C2; B3 = C3;
        }
        if (row + 4 < e) {
            COMPUTE_ROW(A0, A1, A2, A3)
            COMPUTE_ROW(B0, B1, B2, B3)
        } else {
            COMPUTE_ROW(A0, A1, A2, A3)
        }
    }

    // write raw partial (bf16) + (m, denom); no normalization, no barrier.
    if (lane == 0) {
        pmd[bag * 8 + w * 2 + 0] = m;
        pmd[bag * 8 + w * 2 + 1] = denom;
    }
    unsigned short* pr = partial + ((size_t)bag * 4 + w) * CDIM;
    {
        ushort4 o; o.x = f2bf(a0.x); o.y = f2bf(a0.y); o.z = f2bf(a0.z); o.w = f2bf(a0.w);
        *(ushort4*)(pr + 4 * lane) = o;
    }
    {
        ushort4 o; o.x = f2bf(a1.x); o.y = f2bf(a1.y); o.z = f2bf(a1.z); o.w = f2bf(a1.w);
        *(ushort4*)(pr + 256 + 4 * lane) = o;
    }
    {
        ushort4 o; o.x = f2bf(a2.x); o.y = f2bf(a2.y); o.z = f2bf(a2.z); o.w = f2bf(a2.w);
        *(ushort4*)(pr + 512 + 4 * lane) = o;
    }
    {
        ushort4 o; o.x = f2bf(a3.x); o.y = f2bf(a3.y); o.z = f2bf(a3.z); o.w = f2bf(a3.w);
        *(ushort4*)(pr + 768 + 4 * lane) = o;
    }
}

// Kernel 2: MFMA GEMM + deferred softmax combine. Block = 16 bags, 8 waves,
// wave q owns K-chunk [q*128, q*128+128). Prologue computes per-(bag,wave)
// scales sc_p = exp(m_p - ms) / sum_p exp(m_p - ms) * d_p; the A-fragment is
// combined in fp32 from the 4 bf16 partials (L3-resident), then packed bf16
// for the MFMA. B from packed PW (1 KB coalesced loads). LDS reduce as before.
__global__ __launch_bounds__(512) void bag_gemm_merge(
    const unsigned short* __restrict__ partial,
    const float* __restrict__ pmd,
    const unsigned short* __restrict__ PW,
    const float* __restrict__ bias,
    float* __restrict__ out)
{
    const int q    = threadIdx.x >> 6;   // k-chunk 0..7
    const int lane = threadIdx.x & 63;
    const int bag0 = blockIdx.x * 16;
    const int ln15 = lane & 15;
    const int koff = (lane >> 4) * 8;

    __shared__ float   smd[128];
    __shared__ float   ssc[16][4];
    __shared__ floatx4 lds[8][7][64];    // 57 KB

    if (threadIdx.x < 128) smd[threadIdx.x] = pmd[bag0 * 8 + threadIdx.x];
    __syncthreads();
    if (threadIdx.x < 16) {
        const float* pp = &smd[threadIdx.x * 8];
        const float m0 = pp[0], d0 = pp[1], m1 = pp[2], d1 = pp[3];
        const float m2 = pp[4], d2 = pp[5], m3 = pp[6], d3 = pp[7];
        const float ms = fmaxf(fmaxf(m0, m1), fmaxf(m2, m3));
        const float f0 = __expf(m0 - ms);   // empty wave: exp(-inf)=0
        const float f1 = __expf(m1 - ms);
        const float f2 = __expf(m2 - ms);
        const float f3 = __expf(m3 - ms);
        const float inv = 1.0f / (f0 * d0 + f1 * d1 + f2 * d2 + f3 * d3);
        ssc[threadIdx.x][0] = f0 * inv;
        ssc[threadIdx.x][1] = f1 * inv;
        ssc[threadIdx.x][2] = f2 * inv;
        ssc[threadIdx.x][3] = f3 * inv;
    }
    __syncthreads();

    const float s0 = ssc[ln15][0], s1 = ssc[ln15][1];
    const float s2 = ssc[ln15][2], s3 = ssc[ln15][3];

    floatx4 acc[7];
    #pragma unroll
    for (int t = 0; t < 7; ++t) acc[t] = (floatx4){0.f, 0.f, 0.f, 0.f};

    const unsigned short* aBase = partial + (size_t)(bag0 + ln15) * 4 * CDIM + koff;
    const unsigned short* bBase = PW + lane * 8;

    #pragma unroll
    for (int i = 0; i < 4; ++i) {
        const int kc = q * 4 + i;
        const bf16x8 p0 = *(const bf16x8*)(aBase + 0 * CDIM + kc * 32);
        const bf16x8 p1 = *(const bf16x8*)(aBase + 1 * CDIM + kc * 32);
        const bf16x8 p2 = *(const bf16x8*)(aBase + 2 * CDIM + kc * 32);
        const bf16x8 p3 = *(const bf16x8*)(aBase + 3 * CDIM + kc * 32);
        bf16x8 a;
        #pragma unroll
        for (int j = 0; j < 8; ++j) {
            float v = s0 * bf2f((unsigned short)p0[j]);
            v = fmaf(s1, bf2f((unsigned short)p1[j]), v);
            v = fmaf(s2, bf2f((unsigned short)p2[j]), v);
            v = fmaf(s3, bf2f((unsigned short)p3[j]), v);
            a[j] = (short)f2bf(v);
        }
        #pragma unroll
        for (int t = 0; t < 7; ++t) {
            const bf16x8 b = *(const bf16x8*)(bBase + (size_t)(kc * 7 + t) * 512);
            acc[t] = __builtin_amdgcn_mfma_f32_16x16x32_bf16(a, b, acc[t], 0, 0, 0);
        }
    }

    #pragma unroll
    for (int t = 0; t < 7; ++t) lds[q][t][lane] = acc[t];
    __syncthreads();

    // 7 tiles x 64 slots = 448 outputs of 4 bags each, over 512 threads.
    const int p = threadIdx.x;
    if (p < 448) {
        const int t    = p >> 6;
        const int slot = p & 63;
        const int r    = t * 16 + (slot & 15);
        if (r < RDIM) {
            floatx4 s = lds[0][t][slot];
            #pragma unroll
            for (int qq = 1; qq < 8; ++qq) s += lds[qq][t][slot];
            const float bv = bias[r];
            const int bagr = bag0 + (slot >> 4) * 4;
            out[(size_t)(bagr + 0) * RDIM + r] = s[0] + bv;
            out[(size_t)(bagr + 1) * RDIM + r] = s[1] + bv;
            out[(size_t)(bagr + 2) * RDIM + r] = s[2] + bv;
            out[(size_t)(bagr + 3) * RDIM + r] = s[3] + bv;
        }
    }
}

extern "C" void kernel_launch(void* const* d_in, const int* in_sizes, int n_in,
                              void* d_out, int out_size, void* d_ws, size_t ws_size,
                              hipStream_t stream) {
    const float* X    = (const float*)d_in[0];
    const float* Con  = (const float*)d_in[1];
    const float* W    = (const float*)d_in[2];
    const float* bias = (const float*)d_in[3];
    const int* scope  = (const int*)d_in[4];
    const int* rel    = (const int*)d_in[5];
    float* out = (float*)d_out;

    unsigned short* partial = (unsigned short*)d_ws;              // 8192*4*1024*2 = 67.1 MB
    unsigned short* PW      = partial + (size_t)NBAGS * 4 * CDIM; // 112*1024*2    = 0.23 MB
    float* pmd              = (float*)(PW + (size_t)RPAD * CDIM); // 8192*8*4      = 0.26 MB

    bag_softmax_partial<<<NBAGS + RPAD, 256, 0, stream>>>(X, Con, scope, rel, W, partial, pmd, PW);
    bag_gemm_merge<<<NBAGS / 16, 512, 0, stream>>>(partial, pmd, PW, bias, out);
}

// Round 18
// 63.929 us; speedup vs baseline: 1.4144x; 1.4144x over previous
//
#include <hip/hip_runtime.h>
#include <math.h>

#define CDIM 1024
#define RDIM 100
#define NBAGS 8192
#define RPAD 112   // 7 r-tiles of 16

typedef float floatx4 __attribute__((ext_vector_type(4)));
typedef short bf16x8 __attribute__((ext_vector_type(8)));

__device__ __forceinline__ float dot4(float4 a, float4 b) {
    return a.x * b.x + a.y * b.y + a.z * b.z + a.w * b.w;
}

// fp32 -> bf16 round-to-nearest-even
__device__ __forceinline__ unsigned short f2bf(float f) {
    unsigned int u = __builtin_bit_cast(unsigned int, f);
    u += 0x7FFFu + ((u >> 16) & 1u);
    return (unsigned short)(u >> 16);
}

#define LOADROW(D0, D1, D2, D3, ri)                                          \
    {                                                                        \
        const float4* p_ = (const float4*)(X + (size_t)(ri) * CDIM);         \
        D0 = p_[lane];       D1 = p_[lane + 64];                             \
        D2 = p_[lane + 128]; D3 = p_[lane + 192];                            \
    }

// Online-softmax update with one row held in named registers.
#define COMPUTE_ROW(A0, A1, A2, A3)                                          \
    {                                                                        \
        float p = dot4(A0, c0) + dot4(A1, c1) + dot4(A2, c2) + dot4(A3, c3); \
        p += __shfl_xor(p, 1);                                               \
        p += __shfl_xor(p, 2);                                               \
        p += __shfl_xor(p, 4);                                               \
        p += __shfl_xor(p, 8);                                               \
        p += __shfl_xor(p, 16);                                              \
        p += __shfl_xor(p, 32);                                              \
        const float newm = fmaxf(m, p);                                      \
        const float corr = __expf(m - newm);  /* 0 on first row */           \
        const float wgt  = __expf(p - newm);                                 \
        denom = fmaf(denom, corr, wgt);                                      \
        a0.x = fmaf(a0.x, corr, wgt * A0.x); a0.y = fmaf(a0.y, corr, wgt * A0.y); \
        a0.z = fmaf(a0.z, corr, wgt * A0.z); a0.w = fmaf(a0.w, corr, wgt * A0.w); \
        a1.x = fmaf(a1.x, corr, wgt * A1.x); a1.y = fmaf(a1.y, corr, wgt * A1.y); \
        a1.z = fmaf(a1.z, corr, wgt * A1.z); a1.w = fmaf(a1.w, corr, wgt * A1.w); \
        a2.x = fmaf(a2.x, corr, wgt * A2.x); a2.y = fmaf(a2.y, corr, wgt * A2.y); \
        a2.z = fmaf(a2.z, corr, wgt * A2.z); a2.w = fmaf(a2.w, corr, wgt * A2.w); \
        a3.x = fmaf(a3.x, corr, wgt * A3.x); a3.y = fmaf(a3.y, corr, wgt * A3.y); \
        a3.z = fmaf(a3.z, corr, wgt * A3.z); a3.w = fmaf(a3.w, corr, wgt * A3.w); \
        m = newm;                                                            \
    }

// Kernel 1 (round-12 optimum): one BLOCK (4 waves) per bag, rows striped
// across waves (stride 4), per-wave online-softmax state in registers, 2-deep
// prefetch, LDS merge, coalesced row-major bf16 epilogue.
// Blocks >= NBAGS build PW.
// [History: fusion (r13/r15), perm-scheduling (r16) and deferred merge (r17)
//  all regressed vs this structure — see session journal.]
__global__ __launch_bounds__(256) void bag_softmax_kernel(
    const float* __restrict__ X,
    const float* __restrict__ Constraints,
    const int* __restrict__ scope,
    const int* __restrict__ rel,
    const float* __restrict__ W,
    unsigned short* __restrict__ bagbuf,
    unsigned short* __restrict__ PW)
{
    const int lane = threadIdx.x & 63;
    const int w    = threadIdx.x >> 6;

    if (blockIdx.x >= NBAGS) {
        // Build PW: one r-row per block (112 blocks), 4 channels per thread.
        // PW[((kc*7+t)*64 + lane)*8 + i] = W[t*16+(lane&15)][kc*32+(lane>>4)*8+i]
        const int rr = blockIdx.x - NBAGS;          // 0..111
        const int t  = threadIdx.x;                 // channels c = 4t..4t+3
        const int kc  = t >> 3;
        const int sub = (t >> 1) & 3;
        const int i0  = (t & 1) * 4;
        ushort4 o = {0, 0, 0, 0};
        if (rr < RDIM) {
            float4 v = *(const float4*)(W + (size_t)rr * CDIM + t * 4);
            o.x = f2bf(v.x); o.y = f2bf(v.y); o.z = f2bf(v.z); o.w = f2bf(v.w);
        }
        const int tt = rr >> 4, rl = rr & 15;
        *(ushort4*)(PW + ((size_t)(kc * 7 + tt) * 64 + sub * 16 + rl) * 8 + i0) = o;
        return;
    }

    __shared__ float4 lds_acc[4][256];
    __shared__ float  lds_m[4];
    __shared__ float  lds_d[4];

    const int bag = blockIdx.x;
    const int s = scope[2 * bag];
    const int e = scope[2 * bag + 1];
    const int r = rel[bag];

    const float4* conp = (const float4*)(Constraints + (size_t)r * CDIM);
    const float4 c0 = conp[lane];
    const float4 c1 = conp[lane + 64];
    const float4 c2 = conp[lane + 128];
    const float4 c3 = conp[lane + 192];

    float4 a0 = {0.f, 0.f, 0.f, 0.f};
    float4 a1 = {0.f, 0.f, 0.f, 0.f};
    float4 a2 = {0.f, 0.f, 0.f, 0.f};
    float4 a3 = {0.f, 0.f, 0.f, 0.f};
    float m = -INFINITY;
    float denom = 0.f;

    int row = s + w;
    if (row < e) {                    // uniform per wave
        float4 A0, A1, A2, A3;        // row
        float4 B0, B1, B2, B3;        // row+4
        float4 C0, C1, C2, C3;        // row+8 (rotating)

        LOADROW(A0, A1, A2, A3, row)
        if (row + 4 < e) LOADROW(B0, B1, B2, B3, row + 4)

        // main loop: runs only while row+8 is a real row (2-deep prefetch)
        for (; row + 8 < e; row += 4) {
            LOADROW(C0, C1, C2, C3, row + 8)
            __builtin_amdgcn_sched_barrier(0);
            COMPUTE_ROW(A0, A1, A2, A3)
            A0 = B0; A1 = B1; A2 = B2; A3 = B3;
            B0 = C0; B1 = C1; B2 = C2; B3 = C3;
        }
        // epilogue: 1 or 2 rows left in registers, zero loads
        if (row + 4 < e) {
            COMPUTE_ROW(A0, A1, A2, A3)
            COMPUTE_ROW(B0, B1, B2, B3)
        } else {
            COMPUTE_ROW(A0, A1, A2, A3)
        }
    }

    if (lane == 0) { lds_m[w] = m; lds_d[w] = denom; }
    lds_acc[w][lane]       = a0;
    lds_acc[w][lane + 64]  = a1;
    lds_acc[w][lane + 128] = a2;
    lds_acc[w][lane + 192] = a3;
    __syncthreads();

    const int t = threadIdx.x;
    const float m0 = lds_m[0], m1 = lds_m[1], m2 = lds_m[2], m3 = lds_m[3];
    const float ms = fmaxf(fmaxf(m0, m1), fmaxf(m2, m3));
    const float f0 = __expf(m0 - ms);   // idle wave: exp(-inf) = 0
    const float f1 = __expf(m1 - ms);
    const float f2 = __expf(m2 - ms);
    const float f3 = __expf(m3 - ms);
    const float dn = f0 * lds_d[0] + f1 * lds_d[1] + f2 * lds_d[2] + f3 * lds_d[3];
    const float inv = 1.0f / dn;

    const float4 v0 = lds_acc[0][t];
    const float4 v1 = lds_acc[1][t];
    const float4 v2 = lds_acc[2][t];
    const float4 v3 = lds_acc[3][t];
    const float ox = (f0 * v0.x + f1 * v1.x + f2 * v2.x + f3 * v3.x) * inv;
    const float oy = (f0 * v0.y + f1 * v1.y + f2 * v2.y + f3 * v3.y) * inv;
    const float oz = (f0 * v0.z + f1 * v1.z + f2 * v2.z + f3 * v3.z) * inv;
    const float ow = (f0 * v0.w + f1 * v1.w + f2 * v2.w + f3 * v3.w) * inv;

    ushort4 o;
    o.x = f2bf(ox); o.y = f2bf(oy); o.z = f2bf(oz); o.w = f2bf(ow);
    *(ushort4*)(bagbuf + (size_t)bag * CDIM + t * 4) = o;   // coalesced
}

// Kernel 2 (round-12): MFMA GEMM, 8-way K-split. Block = 16 bags, 8 waves,
// wave q owns K-chunk [q*128, q*128+128). A gathered from row-major bagbuf;
// B from packed PW (1 KB coalesced loads). Partials reduced through LDS.
__global__ __launch_bounds__(512) void bag_gemm_mfma(
    const unsigned short* __restrict__ bagbuf,
    const unsigned short* __restrict__ PW,
    const float* __restrict__ bias,
    float* __restrict__ out)
{
    const int q    = threadIdx.x >> 6;   // k-chunk 0..7
    const int lane = threadIdx.x & 63;
    const int bag0 = blockIdx.x * 16;
    const int ln15 = lane & 15;
    const int koff = (lane >> 4) * 8;

    __shared__ floatx4 lds[8][7][64];    // 57 KB

    floatx4 acc[7];
    #pragma unroll
    for (int t = 0; t < 7; ++t) acc[t] = (floatx4){0.f, 0.f, 0.f, 0.f};

    const unsigned short* aRow  = bagbuf + (size_t)(bag0 + ln15) * CDIM + koff;
    const unsigned short* bBase = PW + lane * 8;

    #pragma unroll
    for (int i = 0; i < 4; ++i) {
        const int kc = q * 4 + i;
        const bf16x8 a = *(const bf16x8*)(aRow + kc * 32);
        #pragma unroll
        for (int t = 0; t < 7; ++t) {
            const bf16x8 b = *(const bf16x8*)(bBase + (size_t)(kc * 7 + t) * 512);
            acc[t] = __builtin_amdgcn_mfma_f32_16x16x32_bf16(a, b, acc[t], 0, 0, 0);
        }
    }

    #pragma unroll
    for (int t = 0; t < 7; ++t) lds[q][t][lane] = acc[t];
    __syncthreads();

    // 7 tiles x 64 slots = 448 outputs of 4 bags each, over 512 threads.
    const int p = threadIdx.x;
    if (p < 448) {
        const int t    = p >> 6;
        const int slot = p & 63;
        const int r    = t * 16 + (slot & 15);
        if (r < RDIM) {
            floatx4 s = lds[0][t][slot];
            #pragma unroll
            for (int qq = 1; qq < 8; ++qq) s += lds[qq][t][slot];
            const float bv = bias[r];
            const int bagr = bag0 + (slot >> 4) * 4;
            out[(size_t)(bagr + 0) * RDIM + r] = s[0] + bv;
            out[(size_t)(bagr + 1) * RDIM + r] = s[1] + bv;
            out[(size_t)(bagr + 2) * RDIM + r] = s[2] + bv;
            out[(size_t)(bagr + 3) * RDIM + r] = s[3] + bv;
        }
    }
}

extern "C" void kernel_launch(void* const* d_in, const int* in_sizes, int n_in,
                              void* d_out, int out_size, void* d_ws, size_t ws_size,
                              hipStream_t stream) {
    const float* X    = (const float*)d_in[0];
    const float* Con  = (const float*)d_in[1];
    const float* W    = (const float*)d_in[2];
    const float* bias = (const float*)d_in[3];
    const int* scope  = (const int*)d_in[4];
    const int* rel    = (const int*)d_in[5];
    float* out = (float*)d_out;

    unsigned short* bagbuf = (unsigned short*)d_ws;          // 8192*1024*2 = 16.8 MB
    unsigned short* PW     = bagbuf + (size_t)NBAGS * CDIM;  // 112*1024*2  = 0.23 MB

    bag_softmax_kernel<<<NBAGS + RPAD, 256, 0, stream>>>(X, Con, scope, rel, W, bagbuf, PW);
    bag_gemm_mfma<<<NBAGS / 16, 512, 0, stream>>>(bagbuf, PW, bias, out);
}